// Round 9
// baseline (233.086 us; speedup 1.0000x reference)
//
#include <hip/hip_runtime.h>

// VQ: x (16,64,64,64) f32, codebook e (64,1024) f32. N=65536, D=64, K=1024.
//
// R9 = R6's barrier-free K-loop + R3's K-split-across-waves for occupancy:
//  - block = 32 positions (2 M-tiles), wave w scans code tiles [16w,16w+16)
//    directly from L2 (no LDS staging, no in-loop barriers). Grid 2048 ->
//    4+ blocks/CU (R6 was grid-limited to 2).
//  - per-wave regs halved vs R8 (no dbuf state): fits (256,4) w/o spilling.
//  - prep: one 64-block LDS-transpose kernel, coalesced 16 B stores (old
//    preps scattered 2 B stores).
// Numerics = R8 (passed, absmax 0): A-less scores (constant per position),
// split-bf16 3-term MFMA, MARGIN certify vs top-2, np-bit-exact block-local
// fallback with first-index ties.

#define D 64
#define K 1024
#define NPOS 65536
#define HW 4096
#define XSTRIDE 262144  // D*HW
#define MARGIN 1.0e-3f

typedef float vfloat4 __attribute__((ext_vector_type(4)));
typedef short short8  __attribute__((ext_vector_type(8)));

static __device__ __forceinline__ unsigned short bf16_rne(float f) {
    unsigned u = __float_as_uint(f);
    u += 0x7FFFu + ((u >> 16) & 1u);
    return (unsigned short)(u >> 16);
}
static __device__ __forceinline__ float bf16_to_f32(unsigned short h) {
    return __uint_as_float(((unsigned)h) << 16);
}

// ---- prep: 64 blocks, one 16-code tile each; all outputs coalesced ------
__global__ __launch_bounds__(256)
void vq_prep(const float* __restrict__ e, unsigned short* __restrict__ ebf,
             float* __restrict__ eT, float* __restrict__ c2) {
    __shared__ float et[64][17];         // [d][kk], pad 17
    const int tile = blockIdx.x;
    const int t = threadIdx.x;
    const int k0 = tile * 16;
#pragma unroll
    for (int it = 0; it < 4; ++it) {     // coalesced 64 B segments per d
        const int d = it * 16 + (t >> 4);
        et[d][t & 15] = e[d * K + k0 + (t & 15)];
    }
    __syncthreads();
    if (t < 128) {                       // frags: 2 ktiles x 2 splits x 64
        const int s = t >> 6;
        const int lane = t & 63;
        const int n = lane & 15, q = lane >> 4;
        short8 fh, fl_;
#pragma unroll
        for (int j = 0; j < 8; ++j) {
            const int d = s * 32 + q * 8 + j;
            const float v = et[d][n];
            const unsigned short hh = bf16_rne(v);
            fh[j] = (short)hh;
            fl_[j] = (short)bf16_rne(v - bf16_to_f32(hh));  // exact residual
        }
        short8* eb8 = (short8*)ebf;
        eb8[((tile * 2 + s) * 2 + 0) * 64 + lane] = fh;     // 16 B stores
        eb8[((tile * 2 + s) * 2 + 1) * 64 + lane] = fl_;
    }
    {                                    // eT rows: 256 x vfloat4, coalesced
        const int kk = t >> 4, d0 = (t & 15) * 4;
        vfloat4 v;
#pragma unroll
        for (int i = 0; i < 4; ++i) v[i] = et[d0 + i][kk];
        *(vfloat4*)(eT + (size_t)(k0 + kk) * 64 + d0) = v;
    }
    if (t < 16) {                        // c2: np axis-0 sequential order
        float s = 0.f;
#pragma unroll
        for (int d = 0; d < D; ++d) {
            const float v = et[d][t];
            s = s + __fmul_rn(v, v);
        }
        c2[k0 + t] = s;
    }
}

// ---- main: 2048 blocks x 256; block = 32 pos; wave w = K-quarter ---------
__global__ __launch_bounds__(256, 4)
void vq_main(const float* __restrict__ x, const float* __restrict__ e,
             const unsigned short* __restrict__ ebf,
             const float* __restrict__ eT,
             const float* __restrict__ c2g, float* __restrict__ out) {
    __shared__ float c2_lds[K];          // 4 KB
    __shared__ float sS1[4][32], sS2[4][32];
    __shared__ int   sK1[4][32];
    __shared__ float q_lds[32][65];      // 8.3 KB, pad-65
    __shared__ int   bk_lds[32];
    __shared__ int   amb_cnt, amb_list[32];
    __shared__ float xa[64];
    __shared__ float aSh;
    __shared__ float rs[256];
    __shared__ int   rk[256];

    const int t    = threadIdx.x;
    const int lane = t & 63;
    const int w    = t >> 6;             // this wave's K-quarter
    const int n    = lane & 15;          // code col within tile / A-row idx
    const int q    = lane >> 4;          // k-quad / C row group
    const int p0   = blockIdx.x * 32;
    const int b    = p0 >> 12;
    const int sp0  = p0 & (HW - 1);

    if (t == 0) amb_cnt = 0;
    ((vfloat4*)c2_lds)[t] = ((const vfloat4*)c2g)[t];

    // ---- A-frags: all waves share the block's 32 positions (2 M-tiles)
    short8 ah[2][2], al[2][2];
#pragma unroll
    for (int mt = 0; mt < 2; ++mt) {
        const int spc = sp0 + mt * 16 + n;
#pragma unroll
        for (int s = 0; s < 2; ++s) {
            short8 fh, fl_;
#pragma unroll
            for (int j = 0; j < 8; ++j) {
                const int d = s * 32 + q * 8 + j;     // A[m=n][k=q*8+j]
                const float v = x[(size_t)b * XSTRIDE + (size_t)d * HW + spc];
                const unsigned short h = bf16_rne(v);
                fh[j] = (short)h;
                fl_[j] = (short)bf16_rne(v - bf16_to_f32(h));
            }
            ah[mt][s] = fh; al[mt][s] = fl_;
        }
    }
    __syncthreads();                     // c2_lds ready

    float s1v[2][4], s2v[2][4]; int t1v[2][4];
#pragma unroll
    for (int mt = 0; mt < 2; ++mt)
#pragma unroll
        for (int r = 0; r < 4; ++r) { s1v[mt][r] = 3.4e38f; s2v[mt][r] = 3.4e38f; t1v[mt][r] = 0; }

    // ---- barrier-free scan of this wave's 16 tiles (frags straight from L2)
    const short8* fragp = (const short8*)ebf + (size_t)(w * 16) * 256;
    for (int tp = 0; tp < 16; ++tp) {
        const int tile = w * 16 + tp;
        const short8 bh0 = fragp[lane];            // b128 loads, coalesced
        const short8 bl0 = fragp[64 + lane];
        const short8 bh1 = fragp[128 + lane];
        const short8 bl1 = fragp[192 + lane];
        fragp += 256;
        const float c2v = c2_lds[tile * 16 + n];   // LDS broadcast
#pragma unroll
        for (int mt = 0; mt < 2; ++mt) {
            vfloat4 acc = {0.f, 0.f, 0.f, 0.f};    // same order as R6-R8
            acc = __builtin_amdgcn_mfma_f32_16x16x32_bf16(ah[mt][0], bh0, acc, 0, 0, 0);
            acc = __builtin_amdgcn_mfma_f32_16x16x32_bf16(ah[mt][1], bh1, acc, 0, 0, 0);
            acc = __builtin_amdgcn_mfma_f32_16x16x32_bf16(al[mt][0], bh0, acc, 0, 0, 0);
            acc = __builtin_amdgcn_mfma_f32_16x16x32_bf16(al[mt][1], bh1, acc, 0, 0, 0);
            acc = __builtin_amdgcn_mfma_f32_16x16x32_bf16(ah[mt][0], bl0, acc, 0, 0, 0);
            acc = __builtin_amdgcn_mfma_f32_16x16x32_bf16(ah[mt][1], bl1, acc, 0, 0, 0);
#pragma unroll
            for (int r = 0; r < 4; ++r) {          // top-2, s1<=s2 invariant
                const float sc = __builtin_fmaf(-2.f, acc[r], c2v);
                const bool lt1 = sc < s1v[mt][r];
                s2v[mt][r] = fminf(fmaxf(sc, s1v[mt][r]), s2v[mt][r]);
                s1v[mt][r] = fminf(s1v[mt][r], sc);
                t1v[mt][r] = lt1 ? tile : t1v[mt][r];
            }
        }
    }

    // ---- butterfly top-2 over the 16 code-columns, then stash per wave
#pragma unroll
    for (int mt = 0; mt < 2; ++mt)
#pragma unroll
        for (int r = 0; r < 4; ++r) {
            float a1 = s1v[mt][r], a2 = s2v[mt][r];
            int ak = t1v[mt][r] * 16 + n;
#pragma unroll
            for (int m = 1; m < 16; m <<= 1) {
                const float o1 = __shfl_xor(a1, m, 64);
                const float o2 = __shfl_xor(a2, m, 64);
                const int   ok = __shfl_xor(ak, m, 64);
                const bool take = (o1 < a1) || (o1 == a1 && ok < ak);
                const float loser = take ? a1 : o1;
                a1 = take ? o1 : a1;
                ak = take ? ok : ak;
                a2 = fminf(fminf(a2, o2), loser);
            }
            if (n == 0) {
                const int pl = mt * 16 + q * 4 + r;    // position 0..31
                sS1[w][pl] = a1; sS2[w][pl] = a2; sK1[w][pl] = ak;
            }
        }
    __syncthreads();

    // ---- merge the 4 K-ranges (ascending w => ascending k: first-index ok)
    if (t < 32) {
        float bs = sS1[0][t]; int bk = sK1[0][t]; float sec = sS2[0][t];
#pragma unroll
        for (int j = 1; j < 4; ++j) {
            const float a = sS1[j][t]; const int ak = sK1[j][t];
            if (a < bs) { sec = fminf(sec, bs); bs = a; bk = ak; }
            else        { sec = fminf(sec, a); }
            sec = fminf(sec, sS2[j][t]);
        }
        bk_lds[t] = bk;
        if (sec - bs <= MARGIN) {                      // uncertified
            const int i = atomicAdd(&amb_cnt, 1);
            amb_list[i] = t;
        }
    }
    __syncthreads();

    // ---- epilogue: stage winning fp32 rows, then strided-coalesced store
    if (t < 128) {
        const int row = t >> 2, seg = t & 3;
        const float* er = eT + (size_t)bk_lds[row] * 64 + seg * 16;
#pragma unroll
        for (int i = 0; i < 4; ++i)
            *(vfloat4*)(&q_lds[row][seg * 16 + i * 4]) = *(const vfloat4*)(er + i * 4);
    }
    __syncthreads();
    {
        const int pl = t & 31, g = t >> 5;             // 8 channel groups
        const int sp = sp0 + pl;
        const float* xb = x + (size_t)b * XSTRIDE + sp;
        float* ob = out + (size_t)b * XSTRIDE + sp;
#pragma unroll
        for (int i = 0; i < 8; ++i) {
            const int c = g * 8 + i;
            const float xq = xb[(size_t)c * HW];
            const float qv = q_lds[pl][c];
            ob[(size_t)c * HW] = xq + (qv - xq);       // np STE
        }
    }
    __syncthreads();

    // ---- block-local np-bit-exact fallback (rare)
    const int na = amb_cnt;
    for (int ai = 0; ai < na; ++ai) {
        const int pl = amb_list[ai];
        const int sp = sp0 + pl;
        if (t < 64) xa[t] = x[(size_t)b * XSTRIDE + (size_t)t * HW + sp];
        __syncthreads();
        if (t == 0) {                    // np A: pairwise-8, rounded squares
            float r8[8];
#pragma unroll
            for (int i = 0; i < 8; ++i) r8[i] = __fmul_rn(xa[i], xa[i]);
#pragma unroll
            for (int j = 1; j < 8; ++j)
#pragma unroll
                for (int i = 0; i < 8; ++i)
                    r8[i] = r8[i] + __fmul_rn(xa[8 * j + i], xa[8 * j + i]);
            aSh = ((r8[0]+r8[1])+(r8[2]+r8[3])) + ((r8[4]+r8[5])+(r8[6]+r8[7]));
        }
        __syncthreads();
        const float Ap = aSh;
        float bs = 3.4e38f; int bkk = 0x7fffffff;
#pragma unroll
        for (int j = 0; j < 4; ++j) {
            const int k = t + 256 * j;                 // ascending k
            float acc = 0.f;
            for (int d = 0; d < D; ++d)                // sequential-d chain
                acc = __builtin_fmaf(xa[d], e[d * K + k], acc);
            const float sc = __builtin_fmaf(-2.f, acc, Ap) + c2_lds[k];
            if (sc < bs || (sc == bs && k < bkk)) { bs = sc; bkk = k; }
        }
        rs[t] = bs; rk[t] = bkk;
        __syncthreads();
        for (int off = 128; off > 0; off >>= 1) {
            if (t < off) {
                const float so = rs[t + off]; const int ko = rk[t + off];
                if (so < rs[t] || (so == rs[t] && ko < rk[t])) { rs[t] = so; rk[t] = ko; }
            }
            __syncthreads();
        }
        const int kb = rk[0];
        if (t < 64) {
            const float xq = xa[t];
            const float qv = eT[(size_t)kb * 64 + t];
            out[(size_t)b * XSTRIDE + (size_t)t * HW + sp] = xq + (qv - xq);
        }
        __syncthreads();
    }
}

extern "C" void kernel_launch(void* const* d_in, const int* in_sizes, int n_in,
                              void* d_out, int out_size, void* d_ws, size_t ws_size,
                              hipStream_t stream) {
    const float* x = (const float*)d_in[0];
    const float* e = (const float*)d_in[1];
    float* out = (float*)d_out;

    char* ws = (char*)d_ws;                          // 516 KB used
    unsigned short* ebf = (unsigned short*)ws;       // 256 KB B-fragments
    float* eT = (float*)(ws + 262144);               // 256 KB fp32 rows
    float* c2 = (float*)(ws + 524288);               // 4 KB

    vq_prep<<<64, 256, 0, stream>>>(e, ebf, eT, c2);
    vq_main<<<NPOS / 32, 256, 0, stream>>>(x, e, ebf, eT, c2, out);
}

// Round 10
// 150.402 us; speedup vs baseline: 1.5498x; 1.5498x over previous
//
#include <hip/hip_runtime.h>

// VQ: x (16,64,64,64) f32, codebook e (64,1024) f32. N=65536, D=64, K=1024.
//
// R10 = R6 skeleton (best main: 65us; barrier-free K-loop, frags from L2,
// block=128 pos, wave=2 M-tiles scanning ALL 64 tiles) + register software
// pipelining: 4 tiles/iter, ping-pong reg buffers, loads issued ~280 cyc
// ahead of use (covers ~250 cyc L2 latency). (256,2) => 256-VGPR cap, no
// spill (R8/R9 died of spill traffic).
// Carried from R8/R9 (all passed absmax 0): A-less scores, fmed3 top-2,
// block-local np-bit-exact fallback, eT-row epilogue, coalesced prep.

#define D 64
#define K 1024
#define NPOS 65536
#define HW 4096
#define XSTRIDE 262144  // D*HW
#define MARGIN 1.0e-3f

typedef float vfloat4 __attribute__((ext_vector_type(4)));
typedef short short8  __attribute__((ext_vector_type(8)));

static __device__ __forceinline__ unsigned short bf16_rne(float f) {
    unsigned u = __float_as_uint(f);
    u += 0x7FFFu + ((u >> 16) & 1u);
    return (unsigned short)(u >> 16);
}
static __device__ __forceinline__ float bf16_to_f32(unsigned short h) {
    return __uint_as_float(((unsigned)h) << 16);
}

// ---- prep: 64 blocks, one 16-code tile each; all outputs coalesced ------
__global__ __launch_bounds__(256)
void vq_prep(const float* __restrict__ e, unsigned short* __restrict__ ebf,
             float* __restrict__ eT, float* __restrict__ c2) {
    __shared__ float et[64][17];
    const int tile = blockIdx.x;
    const int t = threadIdx.x;
    const int k0 = tile * 16;
#pragma unroll
    for (int it = 0; it < 4; ++it) {
        const int d = it * 16 + (t >> 4);
        et[d][t & 15] = e[d * K + k0 + (t & 15)];
    }
    __syncthreads();
    if (t < 128) {                       // frags: 2 ktiles x 2 splits x 64
        const int s = t >> 6;
        const int lane = t & 63;
        const int n = lane & 15, q = lane >> 4;
        short8 fh, fl_;
#pragma unroll
        for (int j = 0; j < 8; ++j) {
            const int d = s * 32 + q * 8 + j;
            const float v = et[d][n];
            const unsigned short hh = bf16_rne(v);
            fh[j] = (short)hh;
            fl_[j] = (short)bf16_rne(v - bf16_to_f32(hh));
        }
        short8* eb8 = (short8*)ebf;
        eb8[((tile * 2 + s) * 2 + 0) * 64 + lane] = fh;
        eb8[((tile * 2 + s) * 2 + 1) * 64 + lane] = fl_;
    }
    {                                    // eT rows: coalesced vfloat4
        const int kk = t >> 4, d0 = (t & 15) * 4;
        vfloat4 v;
#pragma unroll
        for (int i = 0; i < 4; ++i) v[i] = et[d0 + i][kk];
        *(vfloat4*)(eT + (size_t)(k0 + kk) * 64 + d0) = v;
    }
    if (t < 16) {                        // c2: np axis-0 sequential order
        float s = 0.f;
#pragma unroll
        for (int d = 0; d < D; ++d) {
            const float v = et[d][t];
            s = s + __fmul_rn(v, v);
        }
        c2[k0 + t] = s;
    }
}

// ---- main: 512 blocks x 256; block = 128 pos; wave = 2 M-tiles, full K ---
__global__ __launch_bounds__(256, 2)
void vq_main(const float* __restrict__ x, const float* __restrict__ e,
             const unsigned short* __restrict__ ebf,
             const float* __restrict__ eT,
             const float* __restrict__ c2g, float* __restrict__ out) {
    __shared__ float c2_lds[K];          // 4 KB
    __shared__ float q_lds[64][65];      // 16.6 KB
    __shared__ int   bk_lds[128];
    __shared__ int   amb_cnt, amb_list[128];
    __shared__ float xa[64];
    __shared__ float aSh;
    __shared__ float rs[256];
    __shared__ int   rk[256];

    const int t    = threadIdx.x;
    const int lane = t & 63;
    const int w    = t >> 6;
    const int n    = lane & 15;          // code col in tile / A-row idx
    const int q    = lane >> 4;          // k-quad / C row group
    const int p0   = blockIdx.x * 128;
    const int b    = p0 >> 12;
    const int sp0  = p0 & (HW - 1);

    if (t == 0) amb_cnt = 0;
    ((vfloat4*)c2_lds)[t] = ((const vfloat4*)c2g)[t];

    // ---- A-frags: split-bf16 of this wave's 32 positions (2 M-tiles)
    short8 ah[2][2], al[2][2];
#pragma unroll
    for (int mt = 0; mt < 2; ++mt) {
        const int spc = sp0 + w * 32 + mt * 16 + n;
#pragma unroll
        for (int s = 0; s < 2; ++s) {
            short8 fh, fl_;
#pragma unroll
            for (int j = 0; j < 8; ++j) {
                const int d = s * 32 + q * 8 + j;     // A[m=n][k=q*8+j]
                const float v = x[(size_t)b * XSTRIDE + (size_t)d * HW + spc];
                const unsigned short h = bf16_rne(v);
                fh[j] = (short)h;
                fl_[j] = (short)bf16_rne(v - bf16_to_f32(h));
            }
            ah[mt][s] = fh; al[mt][s] = fl_;
        }
    }
    __syncthreads();                     // c2_lds ready

    float s1v[2][4], s2v[2][4]; int t1v[2][4];
#pragma unroll
    for (int mt = 0; mt < 2; ++mt)
#pragma unroll
        for (int r = 0; r < 4; ++r) { s1v[mt][r] = 3.4e38f; s2v[mt][r] = 3.4e38f; t1v[mt][r] = 0; }

    const short8* __restrict__ ebv = (const short8*)ebf;

#define LOADF(dst, tl)                                                       \
    {                                                                        \
        const short8* fp = ebv + (size_t)(tl) * 256;                         \
        dst[0] = fp[lane];       dst[1] = fp[64 + lane];                     \
        dst[2] = fp[128 + lane]; dst[3] = fp[192 + lane];                    \
    }

#define COMPUTE(buf, tl)                                                     \
    {                                                                        \
        const float c2v = c2_lds[(tl) * 16 + n];                             \
        _Pragma("unroll")                                                    \
        for (int mt = 0; mt < 2; ++mt) {                                     \
            vfloat4 acc = {0.f, 0.f, 0.f, 0.f};                              \
            acc = __builtin_amdgcn_mfma_f32_16x16x32_bf16(ah[mt][0], buf[0], acc, 0, 0, 0); \
            acc = __builtin_amdgcn_mfma_f32_16x16x32_bf16(ah[mt][1], buf[2], acc, 0, 0, 0); \
            acc = __builtin_amdgcn_mfma_f32_16x16x32_bf16(al[mt][0], buf[0], acc, 0, 0, 0); \
            acc = __builtin_amdgcn_mfma_f32_16x16x32_bf16(al[mt][1], buf[2], acc, 0, 0, 0); \
            acc = __builtin_amdgcn_mfma_f32_16x16x32_bf16(ah[mt][0], buf[1], acc, 0, 0, 0); \
            acc = __builtin_amdgcn_mfma_f32_16x16x32_bf16(ah[mt][1], buf[3], acc, 0, 0, 0); \
            _Pragma("unroll")                                                \
            for (int r = 0; r < 4; ++r) {                                    \
                const float sc = __builtin_fmaf(-2.f, acc[r], c2v);          \
                const bool lt1 = sc < s1v[mt][r];                            \
                s2v[mt][r] = __builtin_amdgcn_fmed3f(sc, s1v[mt][r], s2v[mt][r]); \
                s1v[mt][r] = fminf(s1v[mt][r], sc);                          \
                t1v[mt][r] = lt1 ? (tl) : t1v[mt][r];                        \
            }                                                                \
        }                                                                    \
    }

    // buf frag order: [0]=bh0 [1]=bl0 [2]=bh1 [3]=bl1 (tile layout order)
    short8 A0[4], A1[4], B0[4], B1[4];
    LOADF(A0, 0) LOADF(A1, 1)
    for (int s = 0; s < 16; ++s) {       // 4 tiles per iteration
        const int t0 = s * 4;
        LOADF(B0, t0 + 2) LOADF(B1, t0 + 3)        // in flight over A-compute
        COMPUTE(A0, t0) COMPUTE(A1, t0 + 1)
        if (s < 15) { LOADF(A0, t0 + 4) LOADF(A1, t0 + 5) }  // over B-compute
        COMPUTE(B0, t0 + 2) COMPUTE(B1, t0 + 3)
    }
#undef LOADF
#undef COMPUTE

    // ---- butterfly top-2 over 16 code-columns; lane n==0 holds the answer
#pragma unroll
    for (int mt = 0; mt < 2; ++mt)
#pragma unroll
        for (int r = 0; r < 4; ++r) {
            float a1 = s1v[mt][r], a2 = s2v[mt][r];
            int ak = t1v[mt][r] * 16 + n;
#pragma unroll
            for (int m = 1; m < 16; m <<= 1) {
                const float o1 = __shfl_xor(a1, m, 64);
                const float o2 = __shfl_xor(a2, m, 64);
                const int   ok = __shfl_xor(ak, m, 64);
                const bool take = (o1 < a1) || (o1 == a1 && ok < ak);
                const float loser = take ? a1 : o1;
                a1 = take ? o1 : a1;
                ak = take ? ok : ak;
                a2 = fminf(fminf(a2, o2), loser);
            }
            if (n == 0) {
                const int pl = w * 32 + mt * 16 + q * 4 + r;
                bk_lds[pl] = ak;
                if (a2 - a1 <= MARGIN) {               // uncertified
                    const int i = atomicAdd(&amb_cnt, 1);
                    amb_list[i] = pl;
                }
            }
        }
    __syncthreads();

    // ---- epilogue: 2 half-rounds of 64 positions through q_lds
#pragma unroll
    for (int half = 0; half < 2; ++half) {
        {
            const int row = t >> 2, seg = t & 3;
            const float* er = eT + (size_t)bk_lds[half * 64 + row] * 64 + seg * 16;
#pragma unroll
            for (int i = 0; i < 4; ++i)
                *(vfloat4*)(&q_lds[row][seg * 16 + i * 4]) = *(const vfloat4*)(er + i * 4);
        }
        __syncthreads();
        {
            const int pl = t & 63, grp = t >> 6;
            const int sp = sp0 + half * 64 + pl;
            const float* xb = x + (size_t)b * XSTRIDE + sp;
            float* ob = out + (size_t)b * XSTRIDE + sp;
#pragma unroll
            for (int i = 0; i < 16; ++i) {
                const int c = grp * 16 + i;
                const float xq = xb[(size_t)c * HW];
                const float qv = q_lds[pl][c];
                ob[(size_t)c * HW] = xq + (qv - xq);   // np STE
            }
        }
        __syncthreads();
    }

    // ---- block-local np-bit-exact fallback (rare)
    const int na = amb_cnt;
    for (int ai = 0; ai < na; ++ai) {
        const int pl = amb_list[ai];
        const int sp = sp0 + pl;
        if (t < 64) xa[t] = x[(size_t)b * XSTRIDE + (size_t)t * HW + sp];
        __syncthreads();
        if (t == 0) {                    // np A: pairwise-8, rounded squares
            float r8[8];
#pragma unroll
            for (int i = 0; i < 8; ++i) r8[i] = __fmul_rn(xa[i], xa[i]);
#pragma unroll
            for (int j = 1; j < 8; ++j)
#pragma unroll
                for (int i = 0; i < 8; ++i)
                    r8[i] = r8[i] + __fmul_rn(xa[8 * j + i], xa[8 * j + i]);
            aSh = ((r8[0]+r8[1])+(r8[2]+r8[3])) + ((r8[4]+r8[5])+(r8[6]+r8[7]));
        }
        __syncthreads();
        const float Ap = aSh;
        float bs = 3.4e38f; int bkk = 0x7fffffff;
#pragma unroll
        for (int j = 0; j < 4; ++j) {
            const int k = t + 256 * j;                 // ascending k
            float acc = 0.f;
            for (int d = 0; d < D; ++d)                // sequential-d chain
                acc = __builtin_fmaf(xa[d], e[d * K + k], acc);
            const float sc = __builtin_fmaf(-2.f, acc, Ap) + c2_lds[k];
            if (sc < bs || (sc == bs && k < bkk)) { bs = sc; bkk = k; }
        }
        rs[t] = bs; rk[t] = bkk;
        __syncthreads();
        for (int off = 128; off > 0; off >>= 1) {
            if (t < off) {
                const float so = rs[t + off]; const int ko = rk[t + off];
                if (so < rs[t] || (so == rs[t] && ko < rk[t])) { rs[t] = so; rk[t] = ko; }
            }
            __syncthreads();
        }
        const int kb = rk[0];
        if (t < 64) {
            const float xq = xa[t];
            const float qv = eT[(size_t)kb * 64 + t];
            out[(size_t)b * XSTRIDE + (size_t)t * HW + sp] = xq + (qv - xq);
        }
        __syncthreads();
    }
}

extern "C" void kernel_launch(void* const* d_in, const int* in_sizes, int n_in,
                              void* d_out, int out_size, void* d_ws, size_t ws_size,
                              hipStream_t stream) {
    const float* x = (const float*)d_in[0];
    const float* e = (const float*)d_in[1];
    float* out = (float*)d_out;

    char* ws = (char*)d_ws;                          // 516 KB used
    unsigned short* ebf = (unsigned short*)ws;       // 256 KB B-fragments
    float* eT = (float*)(ws + 262144);               // 256 KB fp32 rows
    float* c2 = (float*)(ws + 524288);               // 4 KB

    vq_prep<<<64, 256, 0, stream>>>(e, ebf, eT, c2);
    vq_main<<<NPOS / 128, 256, 0, stream>>>(x, e, ebf, eT, c2, out);
}